// Round 14
// baseline (176.696 us; speedup 1.0000x reference)
//
#include <hip/hip_runtime.h>
#include <stdint.h>

#define NPTS 262144
#define NB 4
#define KSEL 4096
#define CAP 8192
#define SLICE_LEN 1024
#define KBLK 256                   // k_keys blocks per batch
#define WIN_LO 0xB800u             // LDS window: hi16 in [0xB800, 0xC800)
#define WIN_N  0x1000u

// ---- workspace layout (bytes) ----
#define OFF_BITS  0ULL
#define OFF_H16   (4ULL*NPTS*NB)                       // 4 MB keys
#define OFF_CTRL  (OFF_H16 + 4ULL*65536*NB)            // +1 MB h16
#define OFF_GRANK (OFF_CTRL + 1024ULL)
#define OFF_CAND  (OFF_GRANK + 4ULL*CAP*NB)            // +128 KB
#define WS_NEEDED (OFF_CAND + 8ULL*CAP*NB)             // +256 KB

// ---- output layout (float elements) ----
#define OBIN 0
#define ORES (NB*KSEL*5)           // 81920
#define OBOX (ORES + NB*KSEL)      // 98304
#define OCLS (OBOX + NB*KSEL*7)    // 212992

// ctrl per batch (16 u32): [2]=T16 [3]=cand_count [15]=done-counter

__device__ __forceinline__ uint32_t key_of(float mx) {
    uint32_t b = __float_as_uint(mx);
    uint32_t mask = ((int32_t)b >> 31) | 0x80000000u;
    return b ^ mask;
}

// parallel suffix scan over part[0..255] (part[256] must be 0); after call,
// part[i] = sum_{j>=i} original part[j]. All 256 threads participate.
__device__ __forceinline__ void suffix_scan_256(volatile uint32_t* part, int tid) {
    #pragma unroll
    for (int off = 1; off < 256; off <<= 1) {
        uint32_t v = part[tid] + ((tid + off < 256) ? part[tid + off] : 0u);
        __syncthreads();
        part[tid] = v;
        __syncthreads();
    }
}

// ---------------- init: zero h16 + grank + ctrl (deterministic per call) ----------------
__global__ __launch_bounds__(256) void k_init(
    uint4* __restrict__ h16v, uint4* __restrict__ grankv, uint32_t* __restrict__ ctrl)
{
    int bx = blockIdx.x, tid = threadIdx.x;
    uint4 z = make_uint4(0u, 0u, 0u, 0u);
    if (bx < 32) {                                   // h16: 65536 uint4
        int i = bx * 2048 + tid;
        #pragma unroll
        for (int k = 0; k < 8; ++k) h16v[i + k * 256] = z;
    } else {                                         // grank: 8192 uint4 over 8 blocks
        int i = (bx - 32) * 1024 + tid;
        #pragma unroll
        for (int k = 0; k < 4; ++k) grankv[i + k * 256] = z;
        if (bx == 32 && tid < 64) ctrl[tid] = 0u;
    }
}

// ---------------- keys + exact 16-bit histogram; tail (last block/batch) finds T16 ----
__global__ __launch_bounds__(256) void k_keys(
    const float* __restrict__ cls, uint32_t* __restrict__ bits,
    uint32_t* __restrict__ h16, uint32_t* __restrict__ ctrl)
{
    __shared__ uint32_t lh[WIN_N];                   // 16 KB window hist
    __shared__ uint32_t part[257];
    __shared__ uint32_t segS, aboveS;
    __shared__ int amLastS;
    int b = blockIdx.y, bx = blockIdx.x, tid = threadIdx.x;
    for (int i = tid; i < (int)WIN_N; i += 256) lh[i] = 0;
    __syncthreads();

    int chunk = bx * 256 + tid;                      // uint4-chunk in [0, 65536)
    const float4* p = (const float4*)(cls + ((size_t)b * NPTS + (size_t)chunk * 4) * 3);
    float4 v0 = p[0], v1 = p[1], v2 = p[2];
    uint4 o;
    o.x = key_of(fmaxf(fmaxf(v0.x, v0.y), v0.z));
    o.y = key_of(fmaxf(fmaxf(v0.w, v1.x), v1.y));
    o.z = key_of(fmaxf(fmaxf(v1.z, v1.w), v2.x));
    o.w = key_of(fmaxf(fmaxf(v2.y, v2.z), v2.w));
    ((uint4*)(bits + (size_t)b * NPTS))[chunk] = o;
    uint32_t ks[4] = {o.x, o.y, o.z, o.w};
    uint32_t* h16b = h16 + (size_t)b * 65536;
    #pragma unroll
    for (int i = 0; i < 4; ++i) {
        uint32_t hi = ks[i] >> 16;
        uint32_t d = hi - WIN_LO;
        if (d < WIN_N) atomicAdd(&lh[d], 1u);
        else           atomicAdd(&h16b[hi], 1u);     // rare (negatives / tiny)
    }
    __syncthreads();
    for (int i = tid; i < (int)WIN_N; i += 256) {
        uint32_t c = lh[i];
        if (c) atomicAdd(&h16b[WIN_LO + i], c);
    }
    __syncthreads();
    __threadfence();
    if (tid == 0) {
        uint32_t r = atomicAdd(&ctrl[b * 16 + 15], 1u);
        amLastS = (r == (uint32_t)(KBLK - 1));
    }
    __syncthreads();
    if (!amLastS) return;

    // ---- tail: two-level parallel suffix scan of 65536 bins -> T16 ----
    const uint4* h4 = (const uint4*)h16b;
    uint32_t s = 0;
    #pragma unroll 16
    for (int q = 0; q < 64; ++q) {                   // thread t sums bins [t*256, t*256+256)
        uint4 v = h4[tid * 64 + q];
        s += v.x + v.y + v.z + v.w;
    }
    part[tid] = s;
    if (tid == 0) part[256] = 0u;
    __syncthreads();
    suffix_scan_256(part, tid);                      // part[t] = count(hi16 >= t*256)
    if (part[tid] >= (uint32_t)KSEL && part[tid + 1] < (uint32_t)KSEL) segS = (uint32_t)tid;
    __syncthreads();
    if (tid == 0) aboveS = part[segS + 1];
    __syncthreads();
    uint32_t binv = h16b[segS * 256 + tid];
    __syncthreads();
    part[tid] = binv;
    if (tid == 0) part[256] = 0u;
    __syncthreads();
    suffix_scan_256(part, tid);                      // suffix within segment
    {
        uint32_t above = aboveS;
        if (above + part[tid] >= (uint32_t)KSEL && above + part[tid + 1] < (uint32_t)KSEL)
            ctrl[b * 16 + 2] = segS * 256 + (uint32_t)tid;       // T16
    }
}

// ---------------- compact superset (key>>16 >= T16), block-aggregated atomic ----------------
__global__ __launch_bounds__(256) void k_compact(
    const uint32_t* __restrict__ bits, const uint32_t* __restrict__ ctrl,
    uint64_t* __restrict__ cand)
{
    __shared__ uint32_t wbase[4];
    int b = blockIdx.y, tid = threadIdx.x;
    uint32_t T = ctrl[b * 16 + 2];
    const int lane = tid & 63, wave = tid >> 6;
    const uint64_t lmask = (1ull << lane) - 1ull;

    int chunk = blockIdx.x * 256 + tid;
    uint4 v = ((const uint4*)(bits + (size_t)b * NPTS))[chunk];
    uint32_t ks[4] = {v.x, v.y, v.z, v.w};
    bool sel[4];
    #pragma unroll
    for (int i = 0; i < 4; ++i) sel[i] = (ks[i] >> 16) >= T;

    uint32_t wsum = 0;
    #pragma unroll
    for (int i = 0; i < 4; ++i) wsum += (uint32_t)__popcll(__ballot(sel[i]));
    if (lane == 0) wbase[wave] = wsum;
    __syncthreads();
    if (tid == 0) {
        uint32_t c0 = wbase[0], c1 = wbase[1], c2 = wbase[2], c3 = wbase[3];
        uint32_t tot = c0 + c1 + c2 + c3;
        uint32_t base = tot ? atomicAdd((uint32_t*)&ctrl[b * 16 + 3], tot) : 0u;
        wbase[0] = base;
        wbase[1] = base + c0;
        wbase[2] = base + c0 + c1;
        wbase[3] = base + c0 + c1 + c2;
    }
    __syncthreads();
    uint32_t off = wbase[wave];
    #pragma unroll
    for (int i = 0; i < 4; ++i) {
        uint64_t m = __ballot(sel[i]);
        if (sel[i]) {
            uint32_t pos = off + (uint32_t)__popcll(m & lmask);
            if (pos < CAP)
                cand[(size_t)b * CAP + pos] =
                    ((uint64_t)(~ks[i]) << 32) | (uint64_t)((uint32_t)chunk * 4 + i);
        }
        off += (uint32_t)__popcll(m);
    }
}

// ---------------- partial ranks: 4 items/thread per staged LDS slice ----------------
__global__ __launch_bounds__(256) void k_rank1(
    const uint64_t* __restrict__ cand, const uint32_t* __restrict__ ctrl,
    uint32_t* __restrict__ grank)
{
    __shared__ uint64_t keys[SLICE_LEN];
    int b = blockIdx.z;
    uint32_t C = ctrl[b * 16 + 3];
    if (C > CAP) C = CAP;
    uint32_t ig0 = blockIdx.x * 1024;
    uint32_t sk0 = blockIdx.y * SLICE_LEN;
    if (ig0 >= C || sk0 >= C) return;
    uint32_t nk = C - sk0; if (nk > SLICE_LEN) nk = SLICE_LEN;
    const uint64_t* cb = cand + (size_t)b * CAP;
    for (uint32_t i = threadIdx.x; i < nk; i += 256) keys[i] = cb[sk0 + i];
    __syncthreads();
    uint64_t me[4];
    uint32_t idx[4], r[4] = {0u, 0u, 0u, 0u};
    #pragma unroll
    for (int q = 0; q < 4; ++q) {
        idx[q] = ig0 + (uint32_t)q * 256 + threadIdx.x;
        me[q] = (idx[q] < C) ? cb[idx[q]] : ~0ull;
    }
    #pragma unroll 8
    for (uint32_t i = 0; i < nk; ++i) {
        uint64_t k = keys[i];
        r[0] += (k < me[0]) ? 1u : 0u;
        r[1] += (k < me[1]) ? 1u : 0u;
        r[2] += (k < me[2]) ? 1u : 0u;
        r[3] += (k < me[3]) ? 1u : 0u;
    }
    #pragma unroll
    for (int q = 0; q < 4; ++q)
        if (idx[q] < C) atomicAdd(&grank[b * CAP + idx[q]], r[q]);
}

// ---------------- gather by rank ----------------
__global__ __launch_bounds__(256) void k_rank2(
    const uint64_t* __restrict__ cand, const uint32_t* __restrict__ ctrl,
    const uint32_t* __restrict__ grank,
    const float* __restrict__ box, const float* __restrict__ cls, float* __restrict__ out)
{
    int b = blockIdx.y;
    uint32_t C = ctrl[b * 16 + 3];
    if (C > CAP) C = CAP;
    uint32_t item = blockIdx.x * 256 + threadIdx.x;
    if (blockIdx.x * 256 >= C) return;
    if (item >= C) return;
    uint64_t me = cand[(size_t)b * CAP + item];
    uint32_t rank = grank[b * CAP + item];
    if (rank < KSEL) {
        uint32_t n = (uint32_t)me;
        const float* bp = box + ((size_t)b * NPTS + n) * 7;
        float* ob = out + OBOX + ((size_t)b * KSEL + rank) * 7;
        #pragma unroll
        for (int c = 0; c < 7; ++c) ob[c] = bp[c];
        const float* cp = cls + ((size_t)b * NPTS + n) * 3;
        float* oc = out + OCLS + ((size_t)b * KSEL + rank) * 3;
        #pragma unroll
        for (int c = 0; c < 3; ++c) oc[c] = cp[c];
    }
}

// ---------------- fused conv1+bn+relu+conv2+bn+relu+heads ----------------
__global__ __launch_bounds__(256) void k_conv(
    const float* __restrict__ c1w, const float* __restrict__ g1v, const float* __restrict__ b1v,
    const float* __restrict__ m1v, const float* __restrict__ v1v,
    const float* __restrict__ c2w, const float* __restrict__ g2v, const float* __restrict__ b2v,
    const float* __restrict__ m2v, const float* __restrict__ v2v,
    const float* __restrict__ binw, const float* __restrict__ binb,
    const float* __restrict__ resw, const float* __restrict__ resb,
    float* __restrict__ out)
{
    __shared__ __align__(16) float w1s[960];       // [(i*3+tap)*32 + c]
    __shared__ __align__(16) float b1s[32];
    __shared__ __align__(16) float w2s[6144];      // [(i*3+tap)*64 + o]
    __shared__ __align__(16) float b2s[64];
    __shared__ __align__(16) float hws[6][64];     // bin0..4, res
    __shared__ __align__(16) float xin[10][80];
    __shared__ __align__(16) float x1s[32][68];
    __shared__ __align__(16) float x2t[64][68];

    int tid = threadIdx.x;
    int b = blockIdx.y;
    int tile0 = blockIdx.x * 64;
    const float* boxsel = out + OBOX + (size_t)b * KSEL * 7;
    const float* clssel = out + OCLS + (size_t)b * KSEL * 3;

    for (int t = tid; t < 960; t += 256) {
        int c = t / 30, r = t - c * 30, i = r / 3, tap = r - i * 3;
        float inv = g1v[c] * rsqrtf(v1v[c] + 1e-5f);
        w1s[(i * 3 + tap) * 32 + c] = c1w[t] * inv;
    }
    if (tid < 32) {
        float inv = g1v[tid] * rsqrtf(v1v[tid] + 1e-5f);
        b1s[tid] = b1v[tid] - m1v[tid] * inv;
    }
    for (int t = tid; t < 6144; t += 256) {
        int o = t / 96, r = t - o * 96, i = r / 3, tap = r - i * 3;
        float inv = g2v[o] * rsqrtf(v2v[o] + 1e-5f);
        w2s[(i * 3 + tap) * 64 + o] = c2w[t] * inv;
    }
    if (tid >= 64 && tid < 128) {
        int o = tid - 64;
        float inv = g2v[o] * rsqrtf(v2v[o] + 1e-5f);
        b2s[o] = b2v[o] - m2v[o] * inv;
    }
    for (int t = tid; t < 384; t += 256)
        ((float*)hws)[t] = (t < 320) ? binw[t] : resw[t - 320];

    for (int u = tid; u < 680; u += 256) {
        int c = u / 68, k2 = u - c * 68;
        int g = tile0 + k2 - 2;
        float val = 0.f;
        if (g >= 0 && g < KSEL) val = (c < 7) ? boxsel[g * 7 + c] : clssel[g * 3 + (c - 7)];
        xin[c][k2] = val;
    }
    __syncthreads();

    {
        int c = tid & 31, kg = tid >> 5;
        int k0 = kg * 9;
        int nk = 66 - k0; if (nk > 9) nk = 9;
        float a[9];
        #pragma unroll
        for (int kk = 0; kk < 9; ++kk) a[kk] = b1s[c];
        #pragma unroll 2
        for (int i = 0; i < 10; ++i) {
            float xv[11];
            #pragma unroll
            for (int j = 0; j < 11; ++j) xv[j] = xin[i][k0 + j];
            #pragma unroll
            for (int tap = 0; tap < 3; ++tap) {
                float w = w1s[(i * 3 + tap) * 32 + c];
                #pragma unroll
                for (int kk = 0; kk < 9; ++kk) a[kk] = fmaf(w, xv[kk + tap], a[kk]);
            }
        }
        for (int kk = 0; kk < nk; ++kk) {
            int k = k0 + kk, gp = tile0 + k - 1;
            x1s[c][k] = (gp >= 0 && gp < KSEL) ? fmaxf(a[kk], 0.f) : 0.f;
        }
    }
    __syncthreads();

    {
        int o = tid & 63, pg = tid >> 6;
        int p0 = pg * 16;
        float acc[16];
        float bz = b2s[o];
        #pragma unroll
        for (int kk = 0; kk < 16; ++kk) acc[kk] = bz;
        #pragma unroll 4
        for (int i = 0; i < 32; ++i) {
            float4 xq[5];
            const float4* xr = (const float4*)&x1s[i][p0];
            #pragma unroll
            for (int q = 0; q < 5; ++q) xq[q] = xr[q];
            const float* xf = (const float*)xq;
            float w0 = w2s[(i * 3 + 0) * 64 + o];
            float w1 = w2s[(i * 3 + 1) * 64 + o];
            float w2 = w2s[(i * 3 + 2) * 64 + o];
            #pragma unroll
            for (int kk = 0; kk < 16; ++kk) {
                float t0 = fmaf(w0, xf[kk], acc[kk]);
                t0 = fmaf(w1, xf[kk + 1], t0);
                acc[kk] = fmaf(w2, xf[kk + 2], t0);
            }
        }
        #pragma unroll
        for (int kk = 0; kk < 16; ++kk)
            x2t[p0 + kk][o] = fmaxf(acc[kk], 0.f);
    }
    __syncthreads();

    {
        int p = tid & 63, g = tid >> 6;
        const float4* xr = (const float4*)&x2t[p][0];
        const float4* hw4 = (const float4*)hws;
        size_t gpos = (size_t)b * KSEL + (size_t)(tile0 + p);
        if (g < 2) {
            int j0 = g * 2, j1 = j0 + 1;
            float s0 = 0.f, s1 = 0.f;
            #pragma unroll
            for (int q = 0; q < 16; ++q) {
                float4 xv = xr[q];
                float4 wa = hw4[j0 * 16 + q];
                float4 wb = hw4[j1 * 16 + q];
                s0 = fmaf(xv.x, wa.x, s0); s0 = fmaf(xv.y, wa.y, s0);
                s0 = fmaf(xv.z, wa.z, s0); s0 = fmaf(xv.w, wa.w, s0);
                s1 = fmaf(xv.x, wb.x, s1); s1 = fmaf(xv.y, wb.y, s1);
                s1 = fmaf(xv.z, wb.z, s1); s1 = fmaf(xv.w, wb.w, s1);
            }
            out[OBIN + gpos * 5 + j0] = s0 + binb[j0];
            out[OBIN + gpos * 5 + j1] = s1 + binb[j1];
        } else {
            int j = (g == 2) ? 4 : 5;
            float s = 0.f;
            #pragma unroll
            for (int q = 0; q < 16; ++q) {
                float4 xv = xr[q];
                float4 wa = hw4[j * 16 + q];
                s = fmaf(xv.x, wa.x, s); s = fmaf(xv.y, wa.y, s);
                s = fmaf(xv.z, wa.z, s); s = fmaf(xv.w, wa.w, s);
            }
            if (g == 2) out[OBIN + gpos * 5 + 4] = s + binb[4];
            else        out[ORES + gpos]         = s + resb[0];
        }
    }
}

extern "C" void kernel_launch(void* const* d_in, const int* in_sizes, int n_in,
                              void* d_out, int out_size, void* d_ws, size_t ws_size,
                              hipStream_t stream)
{
    const float* box  = (const float*)d_in[0];
    const float* cls  = (const float*)d_in[1];
    const float* c1w  = (const float*)d_in[2];
    const float* g1   = (const float*)d_in[3];
    const float* b1   = (const float*)d_in[4];
    const float* m1   = (const float*)d_in[5];
    const float* v1   = (const float*)d_in[6];
    const float* c2w  = (const float*)d_in[7];
    const float* g2   = (const float*)d_in[8];
    const float* b2   = (const float*)d_in[9];
    const float* m2   = (const float*)d_in[10];
    const float* v2   = (const float*)d_in[11];
    const float* binw = (const float*)d_in[12];
    const float* binb = (const float*)d_in[13];
    const float* resw = (const float*)d_in[14];
    const float* resb = (const float*)d_in[15];
    float* out = (float*)d_out;
    char* ws = (char*)d_ws;
    if (ws_size < WS_NEEDED) return;

    uint32_t* bits  = (uint32_t*)(ws + OFF_BITS);
    uint32_t* h16   = (uint32_t*)(ws + OFF_H16);
    uint32_t* ctrl  = (uint32_t*)(ws + OFF_CTRL);
    uint32_t* grank = (uint32_t*)(ws + OFF_GRANK);
    uint64_t* cand  = (uint64_t*)(ws + OFF_CAND);

    k_init<<<40, 256, 0, stream>>>((uint4*)h16, (uint4*)grank, ctrl);
    k_keys<<<dim3(KBLK, NB), 256, 0, stream>>>(cls, bits, h16, ctrl);
    k_compact<<<dim3(256, NB), 256, 0, stream>>>(bits, ctrl, cand);
    k_rank1<<<dim3(CAP / 1024, CAP / 1024, NB), 256, 0, stream>>>(cand, ctrl, grank);
    k_rank2<<<dim3(CAP / 256, NB), 256, 0, stream>>>(cand, ctrl, grank, box, cls, out);
    k_conv<<<dim3(64, NB), 256, 0, stream>>>(c1w, g1, b1, m1, v1, c2w, g2, b2, m2, v2,
                                             binw, binb, resw, resb, out);
}

// Round 15
// 84.975 us; speedup vs baseline: 2.0794x; 2.0794x over previous
//
#include <hip/hip_runtime.h>
#include <stdint.h>

#define NPTS 262144
#define NB 4
#define KSEL 4096
#define CAP 8192
#define SLICE_LEN 1024
#define CBLK 128                   // compact blocks per batch
#define HBLK 64                    // hist blocks per batch

// ---- workspace layout (bytes) ----
#define OFF_BITS  0ULL
#define OFF_H8P   (4ULL*NPTS*NB)                       // 4 MB (keys)
#define OFF_H12   (OFF_H8P + 4ULL*256*HBLK*NB)         // +256 KB (h8 partials)
#define OFF_CTRL  (OFF_H12 + 4ULL*4096*NB)             // +64 KB
#define OFF_GRANK (OFF_CTRL + 1024ULL)
#define OFF_CAND  (OFF_GRANK + 4ULL*CAP*NB)            // +128 KB
#define WS_NEEDED (OFF_CAND + 8ULL*CAP*NB)             // +256 KB

// ---- output layout (float elements) ----
#define OBIN 0
#define ORES (NB*KSEL*5)           // 81920
#define OBOX (ORES + NB*KSEL)      // 98304
#define OCLS (OBOX + NB*KSEL*7)    // 212992

// ctrl per batch (16 u32): [0]=P8 [1]=count_above_P8 [3]=cand_count [4..11]=rank done-counters

__device__ __forceinline__ uint32_t key_of(float mx) {
    uint32_t b = __float_as_uint(mx);
    uint32_t mask = ((int32_t)b >> 31) | 0x80000000u;
    return b ^ mask;
}

// parallel suffix scan over part[0..255] (part[256] must be 0)
__device__ __forceinline__ void suffix_scan_256(volatile uint32_t* part, int tid) {
    #pragma unroll
    for (int off = 1; off < 256; off <<= 1) {
        uint32_t v = part[tid] + ((tid + off < 256) ? part[tid + off] : 0u);
        __syncthreads();
        part[tid] = v;
        __syncthreads();
    }
}

// ---------------- keys + per-block hi8 partials (16 sub-hists); folds zeroing ----------------
__global__ __launch_bounds__(256) void k_score_hist(
    const float* __restrict__ cls, uint32_t* __restrict__ bits, uint32_t* __restrict__ h8p,
    uint32_t* __restrict__ h12, uint32_t* __restrict__ grank, uint32_t* __restrict__ ctrl)
{
    __shared__ uint32_t lh[16][256];
    for (int i = threadIdx.x; i < 4096; i += 256) ((uint32_t*)lh)[i] = 0;
    __syncthreads();
    int b = blockIdx.y, bx = blockIdx.x;
    int sub = threadIdx.x >> 4;              // 16 sub-hists: halves hot-bin serialization
    for (int it = 0; it < 4; ++it) {
        int chunk = bx * 1024 + it * 256 + threadIdx.x;            // uint4-chunk in [0,65536)
        const float4* p = (const float4*)(cls + ((size_t)b * NPTS + (size_t)chunk * 4) * 3);
        float4 v0 = p[0], v1 = p[1], v2 = p[2];
        uint4 o;
        o.x = key_of(fmaxf(fmaxf(v0.x, v0.y), v0.z));
        o.y = key_of(fmaxf(fmaxf(v0.w, v1.x), v1.y));
        o.z = key_of(fmaxf(fmaxf(v1.z, v1.w), v2.x));
        o.w = key_of(fmaxf(fmaxf(v2.y, v2.z), v2.w));
        ((uint4*)(bits + (size_t)b * NPTS))[chunk] = o;
        atomicAdd(&lh[sub][o.x >> 24], 1u);
        atomicAdd(&lh[sub][o.y >> 24], 1u);
        atomicAdd(&lh[sub][o.z >> 24], 1u);
        atomicAdd(&lh[sub][o.w >> 24], 1u);
    }
    // folded zeroing (visible to later dispatches)
    if (bx == 1) {
        uint4* z = (uint4*)(h12 + (size_t)b * 4096);
        #pragma unroll
        for (int i = 0; i < 4; ++i) z[threadIdx.x + i * 256] = make_uint4(0u, 0u, 0u, 0u);
    } else if (bx == 2) {
        uint4* zg = (uint4*)(grank + (size_t)b * CAP);
        #pragma unroll
        for (int i = 0; i < 8; ++i) zg[threadIdx.x + i * 256] = make_uint4(0u, 0u, 0u, 0u);
    } else if (bx == 3 && threadIdx.x < 9) {
        ctrl[b * 16 + 3 + threadIdx.x] = 0u;   // cand_count + 8 rank done-counters
    }
    __syncthreads();
    uint32_t c = 0;
    #pragma unroll
    for (int s = 0; s < 16; ++s) c += lh[s][threadIdx.x];
    h8p[((size_t)b * HBLK + bx) * 256 + threadIdx.x] = c;          // plain store
}

// ---------------- hist12: inline parallel scan8 for P8 ----------------
__global__ __launch_bounds__(256) void k_hist12(
    const uint32_t* __restrict__ bits, const uint32_t* __restrict__ h8p,
    uint32_t* __restrict__ ctrl, uint32_t* __restrict__ h12)
{
    __shared__ uint32_t lh[4096];
    __shared__ uint32_t part[257];
    __shared__ uint32_t P8s;
    int b = blockIdx.y, bx = blockIdx.x;
    int tid = threadIdx.x;
    for (int i = tid; i < 4096; i += 256) lh[i] = 0;
    uint32_t sum = 0;
    const uint32_t* hp = h8p + (size_t)b * HBLK * 256 + tid;
    #pragma unroll 8
    for (int blk = 0; blk < HBLK; ++blk) sum += hp[blk * 256];
    part[tid] = sum;
    if (tid == 0) part[256] = 0u;
    __syncthreads();
    suffix_scan_256(part, tid);
    {
        uint32_t si = part[tid], sn = part[tid + 1];
        if (si >= (uint32_t)KSEL && sn < (uint32_t)KSEL) {
            P8s = (uint32_t)tid;
            if (bx == 0) { ctrl[b * 16 + 0] = (uint32_t)tid; ctrl[b * 16 + 1] = sn; }
        }
    }
    __syncthreads();
    const uint32_t P8 = P8s;
    for (int it = 0; it < 4; ++it) {
        int chunk = bx * 1024 + it * 256 + tid;
        uint4 v = ((const uint4*)(bits + (size_t)b * NPTS))[chunk];
        if ((v.x >> 24) == P8) atomicAdd(&lh[(v.x >> 12) & 0xFFFu], 1u);
        if ((v.y >> 24) == P8) atomicAdd(&lh[(v.y >> 12) & 0xFFFu], 1u);
        if ((v.z >> 24) == P8) atomicAdd(&lh[(v.z >> 12) & 0xFFFu], 1u);
        if ((v.w >> 24) == P8) atomicAdd(&lh[(v.w >> 12) & 0xFFFu], 1u);
    }
    __syncthreads();
    for (int i = tid; i < 4096; i += 256) {
        uint32_t c = lh[i];
        if (c) atomicAdd(&h12[(size_t)b * 4096 + i], c);
    }
}

// ---------------- compact: inline parallel scan12 for T20 ----------------
__global__ __launch_bounds__(256) void k_compact(
    const uint32_t* __restrict__ bits, const uint32_t* __restrict__ h12,
    uint32_t* __restrict__ ctrl, uint64_t* __restrict__ cand)
{
    __shared__ uint32_t bins[4096];
    __shared__ uint32_t part[257];
    __shared__ uint32_t segS, Ts;
    __shared__ uint32_t wbase[4];
    int b = blockIdx.y, bx = blockIdx.x;
    int tid = threadIdx.x;
    const uint4* src = (const uint4*)(h12 + (size_t)b * 4096);
    for (int i = tid; i < 1024; i += 256) ((uint4*)bins)[i] = src[i];
    __syncthreads();
    {
        uint32_t s = 0;
        int base2 = tid * 16;
        #pragma unroll
        for (int j = 0; j < 16; ++j) s += bins[base2 + j];
        part[tid] = s;
        if (tid == 0) part[256] = 0u;
    }
    __syncthreads();
    const uint32_t K = (uint32_t)KSEL - ctrl[b * 16 + 1];
    suffix_scan_256(part, tid);
    {
        uint32_t si = part[tid], sn = part[tid + 1];
        if (si >= K && sn < K) segS = (uint32_t)tid;
    }
    __syncthreads();
    if (tid < 16) {
        uint32_t seg = segS;
        uint32_t above = part[seg + 1];
        uint32_t cnt = above;
        for (int j = 15; j >= tid; --j) cnt += bins[seg * 16 + j];
        uint32_t cntn = cnt - bins[seg * 16 + tid];
        if (cnt >= K && cntn < K)
            Ts = (ctrl[b * 16 + 0] << 12) | (seg * 16 + (uint32_t)tid);
    }
    __syncthreads();
    const uint32_t T = Ts;
    const int lane = tid & 63, wave = tid >> 6;
    const uint64_t lmask = (1ull << lane) - 1ull;

    int chunk0 = bx * 512 + tid;
    const uint4* sb = (const uint4*)(bits + (size_t)b * NPTS);
    uint4 v0 = sb[chunk0];
    uint4 v1 = sb[chunk0 + 256];
    uint32_t ks[8] = {v0.x, v0.y, v0.z, v0.w, v1.x, v1.y, v1.z, v1.w};
    bool sel[8];
    #pragma unroll
    for (int i = 0; i < 8; ++i) sel[i] = (ks[i] >> 12) >= T;

    uint32_t wsum = 0;
    #pragma unroll
    for (int i = 0; i < 8; ++i) wsum += (uint32_t)__popcll(__ballot(sel[i]));
    if (lane == 0) wbase[wave] = wsum;
    __syncthreads();
    if (tid == 0) {
        uint32_t c0 = wbase[0], c1 = wbase[1], c2 = wbase[2], c3 = wbase[3];
        uint32_t tot = c0 + c1 + c2 + c3;
        uint32_t base = tot ? atomicAdd(&ctrl[b * 16 + 3], tot) : 0u;
        wbase[0] = base;
        wbase[1] = base + c0;
        wbase[2] = base + c0 + c1;
        wbase[3] = base + c0 + c1 + c2;
    }
    __syncthreads();
    uint32_t off = wbase[wave];
    #pragma unroll
    for (int i = 0; i < 8; ++i) {
        uint64_t m = __ballot(sel[i]);
        if (sel[i]) {
            uint32_t pos = off + (uint32_t)__popcll(m & lmask);
            uint32_t n = (uint32_t)(chunk0 + (i < 4 ? 0 : 256)) * 4 + (uint32_t)(i & 3);
            if (pos < CAP)
                cand[(size_t)b * CAP + pos] = ((uint64_t)(~ks[i]) << 32) | (uint64_t)n;
        }
        off += (uint32_t)__popcll(m);
    }
}

// ---------------- rank + fused gather (done-counter per item-group) ----------------
// grid (CAP/1024 item-groups, CAP/1024 slices, NB)
__global__ __launch_bounds__(256) void k_rank(
    const uint64_t* __restrict__ cand, uint32_t* __restrict__ ctrl,
    uint32_t* __restrict__ grank,
    const float* __restrict__ box, const float* __restrict__ cls, float* __restrict__ out)
{
    __shared__ uint64_t keys[SLICE_LEN];
    __shared__ int lastS;
    int b = blockIdx.z, tid = threadIdx.x;
    uint32_t C = ctrl[b * 16 + 3];
    if (C > CAP) C = CAP;
    uint32_t ig = blockIdx.x;
    uint32_t ig0 = ig * 1024;
    uint32_t sk0 = blockIdx.y * SLICE_LEN;
    if (ig0 >= C || sk0 >= C) return;                 // uniform early-exit
    uint32_t Sact = (C + SLICE_LEN - 1) / SLICE_LEN;  // # contributing slice-blocks
    uint32_t nk = C - sk0; if (nk > SLICE_LEN) nk = SLICE_LEN;
    const uint64_t* cb = cand + (size_t)b * CAP;
    for (uint32_t i = tid; i < nk; i += 256) keys[i] = cb[sk0 + i];
    __syncthreads();
    uint64_t me[4];
    uint32_t idx[4], r[4] = {0u, 0u, 0u, 0u};
    #pragma unroll
    for (int q = 0; q < 4; ++q) {
        idx[q] = ig0 + (uint32_t)q * 256 + tid;
        me[q] = (idx[q] < C) ? cb[idx[q]] : ~0ull;
    }
    #pragma unroll 8
    for (uint32_t i = 0; i < nk; ++i) {
        uint64_t k = keys[i];
        r[0] += (k < me[0]) ? 1u : 0u;
        r[1] += (k < me[1]) ? 1u : 0u;
        r[2] += (k < me[2]) ? 1u : 0u;
        r[3] += (k < me[3]) ? 1u : 0u;
    }
    #pragma unroll
    for (int q = 0; q < 4; ++q)
        if (idx[q] < C) atomicAdd(&grank[b * CAP + idx[q]], r[q]);
    __syncthreads();          // all lanes' atomics drained (waitcnt before barrier)
    __threadfence();
    if (tid == 0) {
        uint32_t old = atomicAdd(&ctrl[b * 16 + 4 + ig], 1u);
        lastS = (old == Sact - 1);
    }
    __syncthreads();
    if (!lastS) return;
    // gather this item-group (ranks now final)
    #pragma unroll
    for (int q = 0; q < 4; ++q) {
        uint32_t it = ig0 + (uint32_t)q * 256 + tid;
        if (it < C) {
            uint32_t rank = grank[b * CAP + it];
            if (rank < KSEL) {
                uint32_t n = (uint32_t)cb[it];
                const float* bp = box + ((size_t)b * NPTS + n) * 7;
                float* ob = out + OBOX + ((size_t)b * KSEL + rank) * 7;
                #pragma unroll
                for (int c = 0; c < 7; ++c) ob[c] = bp[c];
                const float* cp = cls + ((size_t)b * NPTS + n) * 3;
                float* oc = out + OCLS + ((size_t)b * KSEL + rank) * 3;
                #pragma unroll
                for (int c = 0; c < 3; ++c) oc[c] = cp[c];
            }
        }
    }
}

// ---------------- fused conv: tile 32, grid (128, NB), 2 blocks/CU ----------------
__global__ __launch_bounds__(256) void k_conv(
    const float* __restrict__ c1w, const float* __restrict__ g1v, const float* __restrict__ b1v,
    const float* __restrict__ m1v, const float* __restrict__ v1v,
    const float* __restrict__ c2w, const float* __restrict__ g2v, const float* __restrict__ b2v,
    const float* __restrict__ m2v, const float* __restrict__ v2v,
    const float* __restrict__ binw, const float* __restrict__ binb,
    const float* __restrict__ resw, const float* __restrict__ resb,
    float* __restrict__ out)
{
    __shared__ __align__(16) float w1s[960];       // [(i*3+tap)*32 + c]
    __shared__ __align__(16) float b1s[32];
    __shared__ __align__(16) float w2s[6144];      // [(i*3+tap)*64 + o]
    __shared__ __align__(16) float b2s[64];
    __shared__ __align__(16) float hws[6][64];     // bin0..4, res
    __shared__ __align__(16) float xin[10][40];    // cols 0..35 = global tile0-2+k2
    __shared__ __align__(16) float x1s[32][36];    // cols 0..33 = global tile0-1+k
    __shared__ __align__(16) float x2t[32][68];    // [pos][o]

    int tid = threadIdx.x;
    int b = blockIdx.y;
    int tile0 = blockIdx.x * 32;
    const float* boxsel = out + OBOX + (size_t)b * KSEL * 7;
    const float* clssel = out + OCLS + (size_t)b * KSEL * 3;

    for (int t = tid; t < 960; t += 256) {
        int c = t / 30, r = t - c * 30, i = r / 3, tap = r - i * 3;
        float inv = g1v[c] * rsqrtf(v1v[c] + 1e-5f);
        w1s[(i * 3 + tap) * 32 + c] = c1w[t] * inv;
    }
    if (tid < 32) {
        float inv = g1v[tid] * rsqrtf(v1v[tid] + 1e-5f);
        b1s[tid] = b1v[tid] - m1v[tid] * inv;
    }
    for (int t = tid; t < 6144; t += 256) {
        int o = t / 96, r = t - o * 96, i = r / 3, tap = r - i * 3;
        float inv = g2v[o] * rsqrtf(v2v[o] + 1e-5f);
        w2s[(i * 3 + tap) * 64 + o] = c2w[t] * inv;
    }
    if (tid >= 64 && tid < 128) {
        int o = tid - 64;
        float inv = g2v[o] * rsqrtf(v2v[o] + 1e-5f);
        b2s[o] = b2v[o] - m2v[o] * inv;
    }
    for (int t = tid; t < 384; t += 256)
        ((float*)hws)[t] = (t < 320) ? binw[t] : resw[t - 320];

    // stage input tile (halo 2): 10 x 36
    for (int u = tid; u < 360; u += 256) {
        int c = u / 36, k2 = u - c * 36;
        int g = tile0 + k2 - 2;
        float val = 0.f;
        if (g >= 0 && g < KSEL) val = (c < 7) ? boxsel[g * 7 + c] : clssel[g * 3 + (c - 7)];
        xin[c][k2] = val;
    }
    __syncthreads();

    // conv1: thread (c, kg): up to 5 positions; 34 x1 columns total
    {
        int c = tid & 31, kg = tid >> 5;
        int k0 = kg * 5;
        int nk = 34 - k0; if (nk > 5) nk = 5; if (nk < 0) nk = 0;
        float a[5];
        #pragma unroll
        for (int kk = 0; kk < 5; ++kk) a[kk] = b1s[c];
        if (nk > 0) {
            #pragma unroll 2
            for (int i = 0; i < 10; ++i) {
                float xv[7];
                #pragma unroll
                for (int j = 0; j < 7; ++j) xv[j] = xin[i][k0 + j];
                #pragma unroll
                for (int tap = 0; tap < 3; ++tap) {
                    float w = w1s[(i * 3 + tap) * 32 + c];
                    #pragma unroll
                    for (int kk = 0; kk < 5; ++kk) a[kk] = fmaf(w, xv[kk + tap], a[kk]);
                }
            }
            for (int kk = 0; kk < nk; ++kk) {
                int k = k0 + kk, gp = tile0 + k - 1;
                x1s[c][k] = (gp >= 0 && gp < KSEL) ? fmaxf(a[kk], 0.f) : 0.f;
            }
        }
    }
    __syncthreads();

    // conv2: thread (o, pg): 8 positions
    {
        int o = tid & 63, pg = tid >> 6;
        int p0 = pg * 8;
        float acc[8];
        float bz = b2s[o];
        #pragma unroll
        for (int kk = 0; kk < 8; ++kk) acc[kk] = bz;
        #pragma unroll 4
        for (int i = 0; i < 32; ++i) {
            float4 xq[3];
            const float4* xr = (const float4*)&x1s[i][p0];
            #pragma unroll
            for (int q = 0; q < 3; ++q) xq[q] = xr[q];
            const float* xf = (const float*)xq;
            float w0 = w2s[(i * 3 + 0) * 64 + o];
            float w1 = w2s[(i * 3 + 1) * 64 + o];
            float w2 = w2s[(i * 3 + 2) * 64 + o];
            #pragma unroll
            for (int kk = 0; kk < 8; ++kk) {
                float t0 = fmaf(w0, xf[kk], acc[kk]);
                t0 = fmaf(w1, xf[kk + 1], t0);
                acc[kk] = fmaf(w2, xf[kk + 2], t0);
            }
        }
        #pragma unroll
        for (int kk = 0; kk < 8; ++kk)
            x2t[p0 + kk][o] = fmaxf(acc[kk], 0.f);
    }
    __syncthreads();

    // heads: thread (p, g): g<5 -> bin j=g; g==5 -> res; g=6,7 idle
    {
        int p = tid & 31, g = tid >> 5;
        if (g < 6) {
            const float4* xr = (const float4*)&x2t[p][0];
            const float4* hw4 = (const float4*)hws;
            size_t gpos = (size_t)b * KSEL + (size_t)(tile0 + p);
            float s = 0.f;
            #pragma unroll
            for (int q = 0; q < 16; ++q) {
                float4 xv = xr[q];
                float4 wa = hw4[g * 16 + q];
                s = fmaf(xv.x, wa.x, s); s = fmaf(xv.y, wa.y, s);
                s = fmaf(xv.z, wa.z, s); s = fmaf(xv.w, wa.w, s);
            }
            if (g < 5) out[OBIN + gpos * 5 + g] = s + binb[g];
            else       out[ORES + gpos]         = s + resb[0];
        }
    }
}

extern "C" void kernel_launch(void* const* d_in, const int* in_sizes, int n_in,
                              void* d_out, int out_size, void* d_ws, size_t ws_size,
                              hipStream_t stream)
{
    const float* box  = (const float*)d_in[0];
    const float* cls  = (const float*)d_in[1];
    const float* c1w  = (const float*)d_in[2];
    const float* g1   = (const float*)d_in[3];
    const float* b1   = (const float*)d_in[4];
    const float* m1   = (const float*)d_in[5];
    const float* v1   = (const float*)d_in[6];
    const float* c2w  = (const float*)d_in[7];
    const float* g2   = (const float*)d_in[8];
    const float* b2   = (const float*)d_in[9];
    const float* m2   = (const float*)d_in[10];
    const float* v2   = (const float*)d_in[11];
    const float* binw = (const float*)d_in[12];
    const float* binb = (const float*)d_in[13];
    const float* resw = (const float*)d_in[14];
    const float* resb = (const float*)d_in[15];
    float* out = (float*)d_out;
    char* ws = (char*)d_ws;
    if (ws_size < WS_NEEDED) return;

    uint32_t* bits  = (uint32_t*)(ws + OFF_BITS);
    uint32_t* h8p   = (uint32_t*)(ws + OFF_H8P);
    uint32_t* h12   = (uint32_t*)(ws + OFF_H12);
    uint32_t* ctrl  = (uint32_t*)(ws + OFF_CTRL);
    uint32_t* grank = (uint32_t*)(ws + OFF_GRANK);
    uint64_t* cand  = (uint64_t*)(ws + OFF_CAND);

    k_score_hist<<<dim3(HBLK, NB), 256, 0, stream>>>(cls, bits, h8p, h12, grank, ctrl);
    k_hist12<<<dim3(HBLK, NB), 256, 0, stream>>>(bits, h8p, ctrl, h12);
    k_compact<<<dim3(CBLK, NB), 256, 0, stream>>>(bits, h12, ctrl, cand);
    k_rank<<<dim3(CAP / 1024, CAP / 1024, NB), 256, 0, stream>>>(cand, ctrl, grank, box, cls, out);
    k_conv<<<dim3(128, NB), 256, 0, stream>>>(c1w, g1, b1, m1, v1, c2w, g2, b2, m2, v2,
                                              binw, binb, resw, resb, out);
}

// Round 16
// 68.889 us; speedup vs baseline: 2.5650x; 1.2335x over previous
//
#include <hip/hip_runtime.h>
#include <stdint.h>

#define NPTS 262144
#define NB 4
#define KSEL 4096
#define CAP 8192
#define SLICE_LEN 1024
#define CBLK 128                   // compact blocks per batch
#define HBLK 64                    // hist blocks per batch

// ---- workspace layout (bytes) ----
#define OFF_BITS  0ULL
#define OFF_H8P   (4ULL*NPTS*NB)                       // 4 MB (keys)
#define OFF_H12   (OFF_H8P + 4ULL*256*HBLK*NB)         // +256 KB (h8 partials)
#define OFF_CTRL  (OFF_H12 + 4ULL*4096*NB)             // +64 KB
#define OFF_GRANK (OFF_CTRL + 1024ULL)
#define OFF_CAND  (OFF_GRANK + 4ULL*CAP*NB)            // +128 KB
#define WS_NEEDED (OFF_CAND + 8ULL*CAP*NB)             // +256 KB

// ---- output layout (float elements) ----
#define OBIN 0
#define ORES (NB*KSEL*5)           // 81920
#define OBOX (ORES + NB*KSEL)      // 98304
#define OCLS (OBOX + NB*KSEL*7)    // 212992

// ctrl per batch (16 u32): [0]=P8 [1]=count_above_P8 [3]=cand_count

__device__ __forceinline__ uint32_t key_of(float mx) {
    uint32_t b = __float_as_uint(mx);
    uint32_t mask = ((int32_t)b >> 31) | 0x80000000u;
    return b ^ mask;
}

// parallel suffix scan over part[0..255] (part[256] must be 0)
__device__ __forceinline__ void suffix_scan_256(volatile uint32_t* part, int tid) {
    #pragma unroll
    for (int off = 1; off < 256; off <<= 1) {
        uint32_t v = part[tid] + ((tid + off < 256) ? part[tid + off] : 0u);
        __syncthreads();
        part[tid] = v;
        __syncthreads();
    }
}

// ---------------- keys + per-block hi8 partials; folds h12/grank/ctrl zeroing ----------------
__global__ __launch_bounds__(256) void k_score_hist(
    const float* __restrict__ cls, uint32_t* __restrict__ bits, uint32_t* __restrict__ h8p,
    uint32_t* __restrict__ h12, uint32_t* __restrict__ grank, uint32_t* __restrict__ ctrl)
{
    __shared__ uint32_t lh[8][256];
    for (int i = threadIdx.x; i < 2048; i += 256) ((uint32_t*)lh)[i] = 0;
    __syncthreads();
    int b = blockIdx.y, bx = blockIdx.x;
    int sub = threadIdx.x >> 5;
    for (int it = 0; it < 4; ++it) {
        int chunk = bx * 1024 + it * 256 + threadIdx.x;            // uint4-chunk in [0,65536)
        const float4* p = (const float4*)(cls + ((size_t)b * NPTS + (size_t)chunk * 4) * 3);
        float4 v0 = p[0], v1 = p[1], v2 = p[2];
        uint4 o;
        o.x = key_of(fmaxf(fmaxf(v0.x, v0.y), v0.z));
        o.y = key_of(fmaxf(fmaxf(v0.w, v1.x), v1.y));
        o.z = key_of(fmaxf(fmaxf(v1.z, v1.w), v2.x));
        o.w = key_of(fmaxf(fmaxf(v2.y, v2.z), v2.w));
        ((uint4*)(bits + (size_t)b * NPTS))[chunk] = o;
        atomicAdd(&lh[sub][o.x >> 24], 1u);
        atomicAdd(&lh[sub][o.y >> 24], 1u);
        atomicAdd(&lh[sub][o.z >> 24], 1u);
        atomicAdd(&lh[sub][o.w >> 24], 1u);
    }
    // folded zeroing (visible to later dispatches)
    if (bx == 1) {
        uint4* z = (uint4*)(h12 + (size_t)b * 4096);
        #pragma unroll
        for (int i = 0; i < 4; ++i) z[threadIdx.x + i * 256] = make_uint4(0u, 0u, 0u, 0u);
    } else if (bx == 2) {
        uint4* zg = (uint4*)(grank + (size_t)b * CAP);
        #pragma unroll
        for (int i = 0; i < 8; ++i) zg[threadIdx.x + i * 256] = make_uint4(0u, 0u, 0u, 0u);
    } else if (bx == 3 && threadIdx.x == 0) {
        ctrl[b * 16 + 3] = 0u;
    }
    __syncthreads();
    uint32_t c = 0;
    #pragma unroll
    for (int s = 0; s < 8; ++s) c += lh[s][threadIdx.x];
    h8p[((size_t)b * HBLK + bx) * 256 + threadIdx.x] = c;          // plain store
}

// ---------------- hist12: inline PARALLEL scan8 for P8 ----------------
__global__ __launch_bounds__(256) void k_hist12(
    const uint32_t* __restrict__ bits, const uint32_t* __restrict__ h8p,
    uint32_t* __restrict__ ctrl, uint32_t* __restrict__ h12)
{
    __shared__ uint32_t lh[4096];
    __shared__ uint32_t part[257];
    __shared__ uint32_t P8s;
    int b = blockIdx.y, bx = blockIdx.x;
    int tid = threadIdx.x;
    for (int i = tid; i < 4096; i += 256) lh[i] = 0;
    uint32_t sum = 0;
    const uint32_t* hp = h8p + (size_t)b * HBLK * 256 + tid;
    #pragma unroll 8
    for (int blk = 0; blk < HBLK; ++blk) sum += hp[blk * 256];
    part[tid] = sum;
    if (tid == 0) part[256] = 0u;
    __syncthreads();
    suffix_scan_256(part, tid);            // part[i] = count of keys with hi8 >= i
    {
        uint32_t si = part[tid], sn = part[tid + 1];
        if (si >= (uint32_t)KSEL && sn < (uint32_t)KSEL) {
            P8s = (uint32_t)tid;
            if (bx == 0) { ctrl[b * 16 + 0] = (uint32_t)tid; ctrl[b * 16 + 1] = sn; }
        }
    }
    __syncthreads();
    const uint32_t P8 = P8s;
    for (int it = 0; it < 4; ++it) {
        int chunk = bx * 1024 + it * 256 + tid;
        uint4 v = ((const uint4*)(bits + (size_t)b * NPTS))[chunk];
        if ((v.x >> 24) == P8) atomicAdd(&lh[(v.x >> 12) & 0xFFFu], 1u);
        if ((v.y >> 24) == P8) atomicAdd(&lh[(v.y >> 12) & 0xFFFu], 1u);
        if ((v.z >> 24) == P8) atomicAdd(&lh[(v.z >> 12) & 0xFFFu], 1u);
        if ((v.w >> 24) == P8) atomicAdd(&lh[(v.w >> 12) & 0xFFFu], 1u);
    }
    __syncthreads();
    for (int i = tid; i < 4096; i += 256) {
        uint32_t c = lh[i];
        if (c) atomicAdd(&h12[(size_t)b * 4096 + i], c);
    }
}

// ---------------- compact: inline PARALLEL scan12 for T20 ----------------
__global__ __launch_bounds__(256) void k_compact(
    const uint32_t* __restrict__ bits, const uint32_t* __restrict__ h12,
    uint32_t* __restrict__ ctrl, uint64_t* __restrict__ cand)
{
    __shared__ uint32_t bins[4096];
    __shared__ uint32_t part[257];
    __shared__ uint32_t segS, Ts;
    __shared__ uint32_t wbase[4];
    int b = blockIdx.y, bx = blockIdx.x;
    int tid = threadIdx.x;
    const uint4* src = (const uint4*)(h12 + (size_t)b * 4096);
    for (int i = tid; i < 1024; i += 256) ((uint4*)bins)[i] = src[i];
    __syncthreads();
    {
        uint32_t s = 0;
        int base2 = tid * 16;
        #pragma unroll
        for (int j = 0; j < 16; ++j) s += bins[base2 + j];
        part[tid] = s;
        if (tid == 0) part[256] = 0u;
    }
    __syncthreads();
    const uint32_t K = (uint32_t)KSEL - ctrl[b * 16 + 1];
    suffix_scan_256(part, tid);
    {
        uint32_t si = part[tid], sn = part[tid + 1];
        if (si >= K && sn < K) segS = (uint32_t)tid;
    }
    __syncthreads();
    if (tid < 16) {
        uint32_t seg = segS;
        uint32_t above = part[seg + 1];
        uint32_t cnt = above;
        for (int j = 15; j >= tid; --j) cnt += bins[seg * 16 + j];
        uint32_t cntn = cnt - bins[seg * 16 + tid];
        if (cnt >= K && cntn < K)
            Ts = (ctrl[b * 16 + 0] << 12) | (seg * 16 + (uint32_t)tid);
    }
    __syncthreads();
    const uint32_t T = Ts;
    const int lane = tid & 63, wave = tid >> 6;
    const uint64_t lmask = (1ull << lane) - 1ull;

    int chunk0 = bx * 512 + tid;
    const uint4* sb = (const uint4*)(bits + (size_t)b * NPTS);
    uint4 v0 = sb[chunk0];
    uint4 v1 = sb[chunk0 + 256];
    uint32_t ks[8] = {v0.x, v0.y, v0.z, v0.w, v1.x, v1.y, v1.z, v1.w};
    bool sel[8];
    #pragma unroll
    for (int i = 0; i < 8; ++i) sel[i] = (ks[i] >> 12) >= T;

    uint32_t wsum = 0;
    #pragma unroll
    for (int i = 0; i < 8; ++i) wsum += (uint32_t)__popcll(__ballot(sel[i]));
    if (lane == 0) wbase[wave] = wsum;
    __syncthreads();
    if (tid == 0) {
        uint32_t c0 = wbase[0], c1 = wbase[1], c2 = wbase[2], c3 = wbase[3];
        uint32_t tot = c0 + c1 + c2 + c3;
        uint32_t base = tot ? atomicAdd(&ctrl[b * 16 + 3], tot) : 0u;
        wbase[0] = base;
        wbase[1] = base + c0;
        wbase[2] = base + c0 + c1;
        wbase[3] = base + c0 + c1 + c2;
    }
    __syncthreads();
    uint32_t off = wbase[wave];
    #pragma unroll
    for (int i = 0; i < 8; ++i) {
        uint64_t m = __ballot(sel[i]);
        if (sel[i]) {
            uint32_t pos = off + (uint32_t)__popcll(m & lmask);
            uint32_t n = (uint32_t)(chunk0 + (i < 4 ? 0 : 256)) * 4 + (uint32_t)(i & 3);
            if (pos < CAP)
                cand[(size_t)b * CAP + pos] = ((uint64_t)(~ks[i]) << 32) | (uint64_t)n;
        }
        off += (uint32_t)__popcll(m);
    }
}

// ---------------- partial ranks: 1 item/thread, 1024 blocks (4 blocks/CU TLP) ----------------
// grid (CAP/256 item-blocks, 8 slices, NB)
__global__ __launch_bounds__(256) void k_rank1(
    const uint64_t* __restrict__ cand, const uint32_t* __restrict__ ctrl,
    uint32_t* __restrict__ grank)
{
    __shared__ uint64_t keys[SLICE_LEN];
    int b = blockIdx.z;
    uint32_t C = ctrl[b * 16 + 3];
    if (C > CAP) C = CAP;
    uint32_t ig0 = blockIdx.x * 256;
    uint32_t sk0 = blockIdx.y * SLICE_LEN;
    if (ig0 >= C || sk0 >= C) return;                 // uniform early-exit
    uint32_t nk = C - sk0; if (nk > SLICE_LEN) nk = SLICE_LEN;
    const uint64_t* cb = cand + (size_t)b * CAP;
    for (uint32_t i = threadIdx.x; i < nk; i += 256) keys[i] = cb[sk0 + i];
    __syncthreads();
    uint32_t item = ig0 + threadIdx.x;
    if (item >= C) return;
    uint64_t me = cb[item];
    uint32_t r = 0;
    #pragma unroll 16
    for (uint32_t i = 0; i < nk; ++i) r += (keys[i] < me) ? 1u : 0u;
    atomicAdd(&grank[b * CAP + item], r);
}

// ---------------- gather by rank ----------------
__global__ __launch_bounds__(256) void k_rank2(
    const uint64_t* __restrict__ cand, const uint32_t* __restrict__ ctrl,
    const uint32_t* __restrict__ grank,
    const float* __restrict__ box, const float* __restrict__ cls, float* __restrict__ out)
{
    int b = blockIdx.y;
    uint32_t C = ctrl[b * 16 + 3];
    if (C > CAP) C = CAP;
    uint32_t item = blockIdx.x * 256 + threadIdx.x;
    if (blockIdx.x * 256 >= C) return;
    if (item >= C) return;
    uint64_t me = cand[(size_t)b * CAP + item];
    uint32_t rank = grank[b * CAP + item];
    if (rank < KSEL) {
        uint32_t n = (uint32_t)me;
        const float* bp = box + ((size_t)b * NPTS + n) * 7;
        float* ob = out + OBOX + ((size_t)b * KSEL + rank) * 7;
        #pragma unroll
        for (int c = 0; c < 7; ++c) ob[c] = bp[c];
        const float* cp = cls + ((size_t)b * NPTS + n) * 3;
        float* oc = out + OCLS + ((size_t)b * KSEL + rank) * 3;
        #pragma unroll
        for (int c = 0; c < 3; ++c) oc[c] = cp[c];
    }
}

// ---------------- fused conv1+bn+relu+conv2+bn+relu+heads (tile 64) ----------------
__global__ __launch_bounds__(256) void k_conv(
    const float* __restrict__ c1w, const float* __restrict__ g1v, const float* __restrict__ b1v,
    const float* __restrict__ m1v, const float* __restrict__ v1v,
    const float* __restrict__ c2w, const float* __restrict__ g2v, const float* __restrict__ b2v,
    const float* __restrict__ m2v, const float* __restrict__ v2v,
    const float* __restrict__ binw, const float* __restrict__ binb,
    const float* __restrict__ resw, const float* __restrict__ resb,
    float* __restrict__ out)
{
    __shared__ __align__(16) float w1s[960];       // [(i*3+tap)*32 + c]
    __shared__ __align__(16) float b1s[32];
    __shared__ __align__(16) float w2s[6144];      // [(i*3+tap)*64 + o]
    __shared__ __align__(16) float b2s[64];
    __shared__ __align__(16) float hws[6][64];     // bin0..4, res
    __shared__ __align__(16) float xin[10][80];
    __shared__ __align__(16) float x1s[32][68];
    __shared__ __align__(16) float x2t[64][68];

    int tid = threadIdx.x;
    int b = blockIdx.y;
    int tile0 = blockIdx.x * 64;
    const float* boxsel = out + OBOX + (size_t)b * KSEL * 7;
    const float* clssel = out + OCLS + (size_t)b * KSEL * 3;

    for (int t = tid; t < 960; t += 256) {
        int c = t / 30, r = t - c * 30, i = r / 3, tap = r - i * 3;
        float inv = g1v[c] * rsqrtf(v1v[c] + 1e-5f);
        w1s[(i * 3 + tap) * 32 + c] = c1w[t] * inv;
    }
    if (tid < 32) {
        float inv = g1v[tid] * rsqrtf(v1v[tid] + 1e-5f);
        b1s[tid] = b1v[tid] - m1v[tid] * inv;
    }
    for (int t = tid; t < 6144; t += 256) {
        int o = t / 96, r = t - o * 96, i = r / 3, tap = r - i * 3;
        float inv = g2v[o] * rsqrtf(v2v[o] + 1e-5f);
        w2s[(i * 3 + tap) * 64 + o] = c2w[t] * inv;
    }
    if (tid >= 64 && tid < 128) {
        int o = tid - 64;
        float inv = g2v[o] * rsqrtf(v2v[o] + 1e-5f);
        b2s[o] = b2v[o] - m2v[o] * inv;
    }
    for (int t = tid; t < 384; t += 256)
        ((float*)hws)[t] = (t < 320) ? binw[t] : resw[t - 320];

    for (int u = tid; u < 680; u += 256) {
        int c = u / 68, k2 = u - c * 68;
        int g = tile0 + k2 - 2;
        float val = 0.f;
        if (g >= 0 && g < KSEL) val = (c < 7) ? boxsel[g * 7 + c] : clssel[g * 3 + (c - 7)];
        xin[c][k2] = val;
    }
    __syncthreads();

    {
        int c = tid & 31, kg = tid >> 5;
        int k0 = kg * 9;
        int nk = 66 - k0; if (nk > 9) nk = 9;
        float a[9];
        #pragma unroll
        for (int kk = 0; kk < 9; ++kk) a[kk] = b1s[c];
        #pragma unroll 2
        for (int i = 0; i < 10; ++i) {
            float xv[11];
            #pragma unroll
            for (int j = 0; j < 11; ++j) xv[j] = xin[i][k0 + j];
            #pragma unroll
            for (int tap = 0; tap < 3; ++tap) {
                float w = w1s[(i * 3 + tap) * 32 + c];
                #pragma unroll
                for (int kk = 0; kk < 9; ++kk) a[kk] = fmaf(w, xv[kk + tap], a[kk]);
            }
        }
        for (int kk = 0; kk < nk; ++kk) {
            int k = k0 + kk, gp = tile0 + k - 1;
            x1s[c][k] = (gp >= 0 && gp < KSEL) ? fmaxf(a[kk], 0.f) : 0.f;
        }
    }
    __syncthreads();

    {
        int o = tid & 63, pg = tid >> 6;
        int p0 = pg * 16;
        float acc[16];
        float bz = b2s[o];
        #pragma unroll
        for (int kk = 0; kk < 16; ++kk) acc[kk] = bz;
        #pragma unroll 4
        for (int i = 0; i < 32; ++i) {
            float4 xq[5];
            const float4* xr = (const float4*)&x1s[i][p0];
            #pragma unroll
            for (int q = 0; q < 5; ++q) xq[q] = xr[q];
            const float* xf = (const float*)xq;
            float w0 = w2s[(i * 3 + 0) * 64 + o];
            float w1 = w2s[(i * 3 + 1) * 64 + o];
            float w2 = w2s[(i * 3 + 2) * 64 + o];
            #pragma unroll
            for (int kk = 0; kk < 16; ++kk) {
                float t0 = fmaf(w0, xf[kk], acc[kk]);
                t0 = fmaf(w1, xf[kk + 1], t0);
                acc[kk] = fmaf(w2, xf[kk + 2], t0);
            }
        }
        #pragma unroll
        for (int kk = 0; kk < 16; ++kk)
            x2t[p0 + kk][o] = fmaxf(acc[kk], 0.f);
    }
    __syncthreads();

    {
        int p = tid & 63, g = tid >> 6;
        const float4* xr = (const float4*)&x2t[p][0];
        const float4* hw4 = (const float4*)hws;
        size_t gpos = (size_t)b * KSEL + (size_t)(tile0 + p);
        if (g < 2) {
            int j0 = g * 2, j1 = j0 + 1;
            float s0 = 0.f, s1 = 0.f;
            #pragma unroll
            for (int q = 0; q < 16; ++q) {
                float4 xv = xr[q];
                float4 wa = hw4[j0 * 16 + q];
                float4 wb = hw4[j1 * 16 + q];
                s0 = fmaf(xv.x, wa.x, s0); s0 = fmaf(xv.y, wa.y, s0);
                s0 = fmaf(xv.z, wa.z, s0); s0 = fmaf(xv.w, wa.w, s0);
                s1 = fmaf(xv.x, wb.x, s1); s1 = fmaf(xv.y, wb.y, s1);
                s1 = fmaf(xv.z, wb.z, s1); s1 = fmaf(xv.w, wb.w, s1);
            }
            out[OBIN + gpos * 5 + j0] = s0 + binb[j0];
            out[OBIN + gpos * 5 + j1] = s1 + binb[j1];
        } else {
            int j = (g == 2) ? 4 : 5;
            float s = 0.f;
            #pragma unroll
            for (int q = 0; q < 16; ++q) {
                float4 xv = xr[q];
                float4 wa = hw4[j * 16 + q];
                s = fmaf(xv.x, wa.x, s); s = fmaf(xv.y, wa.y, s);
                s = fmaf(xv.z, wa.z, s); s = fmaf(xv.w, wa.w, s);
            }
            if (g == 2) out[OBIN + gpos * 5 + 4] = s + binb[4];
            else        out[ORES + gpos]         = s + resb[0];
        }
    }
}

extern "C" void kernel_launch(void* const* d_in, const int* in_sizes, int n_in,
                              void* d_out, int out_size, void* d_ws, size_t ws_size,
                              hipStream_t stream)
{
    const float* box  = (const float*)d_in[0];
    const float* cls  = (const float*)d_in[1];
    const float* c1w  = (const float*)d_in[2];
    const float* g1   = (const float*)d_in[3];
    const float* b1   = (const float*)d_in[4];
    const float* m1   = (const float*)d_in[5];
    const float* v1   = (const float*)d_in[6];
    const float* c2w  = (const float*)d_in[7];
    const float* g2   = (const float*)d_in[8];
    const float* b2   = (const float*)d_in[9];
    const float* m2   = (const float*)d_in[10];
    const float* v2   = (const float*)d_in[11];
    const float* binw = (const float*)d_in[12];
    const float* binb = (const float*)d_in[13];
    const float* resw = (const float*)d_in[14];
    const float* resb = (const float*)d_in[15];
    float* out = (float*)d_out;
    char* ws = (char*)d_ws;
    if (ws_size < WS_NEEDED) return;

    uint32_t* bits  = (uint32_t*)(ws + OFF_BITS);
    uint32_t* h8p   = (uint32_t*)(ws + OFF_H8P);
    uint32_t* h12   = (uint32_t*)(ws + OFF_H12);
    uint32_t* ctrl  = (uint32_t*)(ws + OFF_CTRL);
    uint32_t* grank = (uint32_t*)(ws + OFF_GRANK);
    uint64_t* cand  = (uint64_t*)(ws + OFF_CAND);

    k_score_hist<<<dim3(HBLK, NB), 256, 0, stream>>>(cls, bits, h8p, h12, grank, ctrl);
    k_hist12<<<dim3(HBLK, NB), 256, 0, stream>>>(bits, h8p, ctrl, h12);
    k_compact<<<dim3(CBLK, NB), 256, 0, stream>>>(bits, h12, ctrl, cand);
    k_rank1<<<dim3(CAP / 256, 8, NB), 256, 0, stream>>>(cand, ctrl, grank);
    k_rank2<<<dim3(CAP / 256, NB), 256, 0, stream>>>(cand, ctrl, grank, box, cls, out);
    k_conv<<<dim3(64, NB), 256, 0, stream>>>(c1w, g1, b1, m1, v1, c2w, g2, b2, m2, v2,
                                             binw, binb, resw, resb, out);
}

// Round 17
// 68.469 us; speedup vs baseline: 2.5807x; 1.0061x over previous
//
#include <hip/hip_runtime.h>
#include <stdint.h>

#define NPTS 262144
#define NB 4
#define KSEL 4096
#define CAP 8192
#define SLICE_LEN 1024
#define CBLK 128                   // compact blocks per batch
#define HBLK 64                    // score blocks per batch
#define NBIN 8192                  // 13-bit prefix bins (key >> 19)

// ---- workspace layout (bytes) ----
#define OFF_BITS  0ULL
#define OFF_H13   (4ULL*NPTS*NB)                       // 4 MB (keys)
#define OFF_CTRL  (OFF_H13 + 4ULL*NBIN*NB)             // +128 KB h13
#define OFF_GRANK (OFF_CTRL + 1024ULL)
#define OFF_CAND  (OFF_GRANK + 4ULL*CAP*NB)            // +128 KB
#define WS_NEEDED (OFF_CAND + 8ULL*CAP*NB)             // +256 KB

// ---- output layout (float elements) ----
#define OBIN 0
#define ORES (NB*KSEL*5)           // 81920
#define OBOX (ORES + NB*KSEL)      // 98304
#define OCLS (OBOX + NB*KSEL*7)    // 212992

// ctrl per batch (16 u32): [3]=cand_count

__device__ __forceinline__ uint32_t key_of(float mx) {
    uint32_t b = __float_as_uint(mx);
    uint32_t mask = ((int32_t)b >> 31) | 0x80000000u;
    return b ^ mask;
}

// parallel suffix scan over part[0..255] (part[256] must be 0)
__device__ __forceinline__ void suffix_scan_256(volatile uint32_t* part, int tid) {
    #pragma unroll
    for (int off = 1; off < 256; off <<= 1) {
        uint32_t v = part[tid] + ((tid + off < 256) ? part[tid + off] : 0u);
        __syncthreads();
        part[tid] = v;
        __syncthreads();
    }
}

// ---------------- init: zero h13 (8 blocks, one uint4/thread) ----------------
__global__ __launch_bounds__(256) void k_init(uint4* __restrict__ h13v)
{
    h13v[blockIdx.x * 256 + threadIdx.x] = make_uint4(0u, 0u, 0u, 0u);
}

// ---------------- keys + 13-bit LDS histogram (full coverage, no window) ----------------
__global__ __launch_bounds__(256) void k_score(
    const float* __restrict__ cls, uint32_t* __restrict__ bits, uint32_t* __restrict__ h13,
    uint32_t* __restrict__ grank, uint32_t* __restrict__ ctrl)
{
    __shared__ uint32_t lh[NBIN];                      // 32 KB
    for (int i = threadIdx.x; i < NBIN; i += 256) lh[i] = 0;
    __syncthreads();
    int b = blockIdx.y, bx = blockIdx.x;
    for (int it = 0; it < 4; ++it) {
        int chunk = bx * 1024 + it * 256 + threadIdx.x;            // uint4-chunk in [0,65536)
        const float4* p = (const float4*)(cls + ((size_t)b * NPTS + (size_t)chunk * 4) * 3);
        float4 v0 = p[0], v1 = p[1], v2 = p[2];
        uint4 o;
        o.x = key_of(fmaxf(fmaxf(v0.x, v0.y), v0.z));
        o.y = key_of(fmaxf(fmaxf(v0.w, v1.x), v1.y));
        o.z = key_of(fmaxf(fmaxf(v1.z, v1.w), v2.x));
        o.w = key_of(fmaxf(fmaxf(v2.y, v2.z), v2.w));
        ((uint4*)(bits + (size_t)b * NPTS))[chunk] = o;
        atomicAdd(&lh[o.x >> 19], 1u);
        atomicAdd(&lh[o.y >> 19], 1u);
        atomicAdd(&lh[o.z >> 19], 1u);
        atomicAdd(&lh[o.w >> 19], 1u);
    }
    // folded zeroing (visible to later dispatches)
    if (bx == 1) {
        uint4* zg = (uint4*)(grank + (size_t)b * CAP);
        #pragma unroll
        for (int i = 0; i < 8; ++i) zg[threadIdx.x + i * 256] = make_uint4(0u, 0u, 0u, 0u);
    } else if (bx == 2 && threadIdx.x == 0) {
        ctrl[b * 16 + 3] = 0u;
    }
    __syncthreads();
    uint32_t* h13b = h13 + (size_t)b * NBIN;
    for (int i = threadIdx.x; i < NBIN; i += 256) {
        uint32_t c = lh[i];
        if (c) atomicAdd(&h13b[i], c);                 // sparse: few hundred nonzero/block
    }
}

// ---------------- compact: inline parallel scan of 8192 bins -> T13; compact ----------------
__global__ __launch_bounds__(256) void k_compact(
    const uint32_t* __restrict__ bits, const uint32_t* __restrict__ h13,
    uint32_t* __restrict__ ctrl, uint64_t* __restrict__ cand)
{
    __shared__ uint32_t bins[NBIN];                    // 32 KB
    __shared__ uint32_t part[257];
    __shared__ uint32_t segS, Ts;
    __shared__ uint32_t wbase[4];
    int b = blockIdx.y, bx = blockIdx.x;
    int tid = threadIdx.x;
    const uint4* src = (const uint4*)(h13 + (size_t)b * NBIN);
    for (int i = tid; i < NBIN / 4; i += 256) ((uint4*)bins)[i] = src[i];
    __syncthreads();
    {
        uint32_t s = 0;
        int base2 = tid * 32;
        #pragma unroll
        for (int j = 0; j < 32; ++j) s += bins[base2 + j];
        part[tid] = s;
        if (tid == 0) part[256] = 0u;
    }
    __syncthreads();
    suffix_scan_256(part, tid);                        // part[t] = count(bin >= t*32)
    {
        uint32_t si = part[tid], sn = part[tid + 1];
        if (si >= (uint32_t)KSEL && sn < (uint32_t)KSEL) segS = (uint32_t)tid;
    }
    __syncthreads();
    if (tid < 32) {
        uint32_t seg = segS;
        uint32_t above = part[seg + 1];
        uint32_t cnt = above;
        for (int j = 31; j >= tid; --j) cnt += bins[seg * 32 + j];
        uint32_t cntn = cnt - bins[seg * 32 + tid];
        if (cnt >= (uint32_t)KSEL && cntn < (uint32_t)KSEL)
            Ts = seg * 32 + (uint32_t)tid;             // T13
    }
    __syncthreads();
    const uint32_t T = Ts;
    const int lane = tid & 63, wave = tid >> 6;
    const uint64_t lmask = (1ull << lane) - 1ull;

    int chunk0 = bx * 512 + tid;
    const uint4* sb = (const uint4*)(bits + (size_t)b * NPTS);
    uint4 v0 = sb[chunk0];
    uint4 v1 = sb[chunk0 + 256];
    uint32_t ks[8] = {v0.x, v0.y, v0.z, v0.w, v1.x, v1.y, v1.z, v1.w};
    bool sel[8];
    #pragma unroll
    for (int i = 0; i < 8; ++i) sel[i] = (ks[i] >> 19) >= T;

    uint32_t wsum = 0;
    #pragma unroll
    for (int i = 0; i < 8; ++i) wsum += (uint32_t)__popcll(__ballot(sel[i]));
    if (lane == 0) wbase[wave] = wsum;
    __syncthreads();
    if (tid == 0) {
        uint32_t c0 = wbase[0], c1 = wbase[1], c2 = wbase[2], c3 = wbase[3];
        uint32_t tot = c0 + c1 + c2 + c3;
        uint32_t base = tot ? atomicAdd(&ctrl[b * 16 + 3], tot) : 0u;
        wbase[0] = base;
        wbase[1] = base + c0;
        wbase[2] = base + c0 + c1;
        wbase[3] = base + c0 + c1 + c2;
    }
    __syncthreads();
    uint32_t off = wbase[wave];
    #pragma unroll
    for (int i = 0; i < 8; ++i) {
        uint64_t m = __ballot(sel[i]);
        if (sel[i]) {
            uint32_t pos = off + (uint32_t)__popcll(m & lmask);
            uint32_t n = (uint32_t)(chunk0 + (i < 4 ? 0 : 256)) * 4 + (uint32_t)(i & 3);
            if (pos < CAP)
                cand[(size_t)b * CAP + pos] = ((uint64_t)(~ks[i]) << 32) | (uint64_t)n;
        }
        off += (uint32_t)__popcll(m);
    }
}

// ---------------- partial ranks: 1 item/thread, 1024 blocks (4 blocks/CU TLP) ----------------
__global__ __launch_bounds__(256) void k_rank1(
    const uint64_t* __restrict__ cand, const uint32_t* __restrict__ ctrl,
    uint32_t* __restrict__ grank)
{
    __shared__ uint64_t keys[SLICE_LEN];
    int b = blockIdx.z;
    uint32_t C = ctrl[b * 16 + 3];
    if (C > CAP) C = CAP;
    uint32_t ig0 = blockIdx.x * 256;
    uint32_t sk0 = blockIdx.y * SLICE_LEN;
    if (ig0 >= C || sk0 >= C) return;                 // uniform early-exit
    uint32_t nk = C - sk0; if (nk > SLICE_LEN) nk = SLICE_LEN;
    const uint64_t* cb = cand + (size_t)b * CAP;
    for (uint32_t i = threadIdx.x; i < nk; i += 256) keys[i] = cb[sk0 + i];
    __syncthreads();
    uint32_t item = ig0 + threadIdx.x;
    if (item >= C) return;
    uint64_t me = cb[item];
    uint32_t r = 0;
    #pragma unroll 16
    for (uint32_t i = 0; i < nk; ++i) r += (keys[i] < me) ? 1u : 0u;
    atomicAdd(&grank[b * CAP + item], r);
}

// ---------------- gather by rank ----------------
__global__ __launch_bounds__(256) void k_rank2(
    const uint64_t* __restrict__ cand, const uint32_t* __restrict__ ctrl,
    const uint32_t* __restrict__ grank,
    const float* __restrict__ box, const float* __restrict__ cls, float* __restrict__ out)
{
    int b = blockIdx.y;
    uint32_t C = ctrl[b * 16 + 3];
    if (C > CAP) C = CAP;
    uint32_t item = blockIdx.x * 256 + threadIdx.x;
    if (blockIdx.x * 256 >= C) return;
    if (item >= C) return;
    uint64_t me = cand[(size_t)b * CAP + item];
    uint32_t rank = grank[b * CAP + item];
    if (rank < KSEL) {
        uint32_t n = (uint32_t)me;
        const float* bp = box + ((size_t)b * NPTS + n) * 7;
        float* ob = out + OBOX + ((size_t)b * KSEL + rank) * 7;
        #pragma unroll
        for (int c = 0; c < 7; ++c) ob[c] = bp[c];
        const float* cp = cls + ((size_t)b * NPTS + n) * 3;
        float* oc = out + OCLS + ((size_t)b * KSEL + rank) * 3;
        #pragma unroll
        for (int c = 0; c < 3; ++c) oc[c] = cp[c];
    }
}

// ---------------- fused conv1+bn+relu+conv2+bn+relu+heads (tile 64) ----------------
__global__ __launch_bounds__(256) void k_conv(
    const float* __restrict__ c1w, const float* __restrict__ g1v, const float* __restrict__ b1v,
    const float* __restrict__ m1v, const float* __restrict__ v1v,
    const float* __restrict__ c2w, const float* __restrict__ g2v, const float* __restrict__ b2v,
    const float* __restrict__ m2v, const float* __restrict__ v2v,
    const float* __restrict__ binw, const float* __restrict__ binb,
    const float* __restrict__ resw, const float* __restrict__ resb,
    float* __restrict__ out)
{
    __shared__ __align__(16) float w1s[960];       // [(i*3+tap)*32 + c]
    __shared__ __align__(16) float b1s[32];
    __shared__ __align__(16) float w2s[6144];      // [(i*3+tap)*64 + o]
    __shared__ __align__(16) float b2s[64];
    __shared__ __align__(16) float hws[6][64];     // bin0..4, res
    __shared__ __align__(16) float xin[10][80];
    __shared__ __align__(16) float x1s[32][68];
    __shared__ __align__(16) float x2t[64][68];

    int tid = threadIdx.x;
    int b = blockIdx.y;
    int tile0 = blockIdx.x * 64;
    const float* boxsel = out + OBOX + (size_t)b * KSEL * 7;
    const float* clssel = out + OCLS + (size_t)b * KSEL * 3;

    for (int t = tid; t < 960; t += 256) {
        int c = t / 30, r = t - c * 30, i = r / 3, tap = r - i * 3;
        float inv = g1v[c] * rsqrtf(v1v[c] + 1e-5f);
        w1s[(i * 3 + tap) * 32 + c] = c1w[t] * inv;
    }
    if (tid < 32) {
        float inv = g1v[tid] * rsqrtf(v1v[tid] + 1e-5f);
        b1s[tid] = b1v[tid] - m1v[tid] * inv;
    }
    for (int t = tid; t < 6144; t += 256) {
        int o = t / 96, r = t - o * 96, i = r / 3, tap = r - i * 3;
        float inv = g2v[o] * rsqrtf(v2v[o] + 1e-5f);
        w2s[(i * 3 + tap) * 64 + o] = c2w[t] * inv;
    }
    if (tid >= 64 && tid < 128) {
        int o = tid - 64;
        float inv = g2v[o] * rsqrtf(v2v[o] + 1e-5f);
        b2s[o] = b2v[o] - m2v[o] * inv;
    }
    for (int t = tid; t < 384; t += 256)
        ((float*)hws)[t] = (t < 320) ? binw[t] : resw[t - 320];

    for (int u = tid; u < 680; u += 256) {
        int c = u / 68, k2 = u - c * 68;
        int g = tile0 + k2 - 2;
        float val = 0.f;
        if (g >= 0 && g < KSEL) val = (c < 7) ? boxsel[g * 7 + c] : clssel[g * 3 + (c - 7)];
        xin[c][k2] = val;
    }
    __syncthreads();

    {
        int c = tid & 31, kg = tid >> 5;
        int k0 = kg * 9;
        int nk = 66 - k0; if (nk > 9) nk = 9;
        float a[9];
        #pragma unroll
        for (int kk = 0; kk < 9; ++kk) a[kk] = b1s[c];
        #pragma unroll 2
        for (int i = 0; i < 10; ++i) {
            float xv[11];
            #pragma unroll
            for (int j = 0; j < 11; ++j) xv[j] = xin[i][k0 + j];
            #pragma unroll
            for (int tap = 0; tap < 3; ++tap) {
                float w = w1s[(i * 3 + tap) * 32 + c];
                #pragma unroll
                for (int kk = 0; kk < 9; ++kk) a[kk] = fmaf(w, xv[kk + tap], a[kk]);
            }
        }
        for (int kk = 0; kk < nk; ++kk) {
            int k = k0 + kk, gp = tile0 + k - 1;
            x1s[c][k] = (gp >= 0 && gp < KSEL) ? fmaxf(a[kk], 0.f) : 0.f;
        }
    }
    __syncthreads();

    {
        int o = tid & 63, pg = tid >> 6;
        int p0 = pg * 16;
        float acc[16];
        float bz = b2s[o];
        #pragma unroll
        for (int kk = 0; kk < 16; ++kk) acc[kk] = bz;
        #pragma unroll 4
        for (int i = 0; i < 32; ++i) {
            float4 xq[5];
            const float4* xr = (const float4*)&x1s[i][p0];
            #pragma unroll
            for (int q = 0; q < 5; ++q) xq[q] = xr[q];
            const float* xf = (const float*)xq;
            float w0 = w2s[(i * 3 + 0) * 64 + o];
            float w1 = w2s[(i * 3 + 1) * 64 + o];
            float w2 = w2s[(i * 3 + 2) * 64 + o];
            #pragma unroll
            for (int kk = 0; kk < 16; ++kk) {
                float t0 = fmaf(w0, xf[kk], acc[kk]);
                t0 = fmaf(w1, xf[kk + 1], t0);
                acc[kk] = fmaf(w2, xf[kk + 2], t0);
            }
        }
        #pragma unroll
        for (int kk = 0; kk < 16; ++kk)
            x2t[p0 + kk][o] = fmaxf(acc[kk], 0.f);
    }
    __syncthreads();

    {
        int p = tid & 63, g = tid >> 6;
        const float4* xr = (const float4*)&x2t[p][0];
        const float4* hw4 = (const float4*)hws;
        size_t gpos = (size_t)b * KSEL + (size_t)(tile0 + p);
        if (g < 2) {
            int j0 = g * 2, j1 = j0 + 1;
            float s0 = 0.f, s1 = 0.f;
            #pragma unroll
            for (int q = 0; q < 16; ++q) {
                float4 xv = xr[q];
                float4 wa = hw4[j0 * 16 + q];
                float4 wb = hw4[j1 * 16 + q];
                s0 = fmaf(xv.x, wa.x, s0); s0 = fmaf(xv.y, wa.y, s0);
                s0 = fmaf(xv.z, wa.z, s0); s0 = fmaf(xv.w, wa.w, s0);
                s1 = fmaf(xv.x, wb.x, s1); s1 = fmaf(xv.y, wb.y, s1);
                s1 = fmaf(xv.z, wb.z, s1); s1 = fmaf(xv.w, wb.w, s1);
            }
            out[OBIN + gpos * 5 + j0] = s0 + binb[j0];
            out[OBIN + gpos * 5 + j1] = s1 + binb[j1];
        } else {
            int j = (g == 2) ? 4 : 5;
            float s = 0.f;
            #pragma unroll
            for (int q = 0; q < 16; ++q) {
                float4 xv = xr[q];
                float4 wa = hw4[j * 16 + q];
                s = fmaf(xv.x, wa.x, s); s = fmaf(xv.y, wa.y, s);
                s = fmaf(xv.z, wa.z, s); s = fmaf(xv.w, wa.w, s);
            }
            if (g == 2) out[OBIN + gpos * 5 + 4] = s + binb[4];
            else        out[ORES + gpos]         = s + resb[0];
        }
    }
}

extern "C" void kernel_launch(void* const* d_in, const int* in_sizes, int n_in,
                              void* d_out, int out_size, void* d_ws, size_t ws_size,
                              hipStream_t stream)
{
    const float* box  = (const float*)d_in[0];
    const float* cls  = (const float*)d_in[1];
    const float* c1w  = (const float*)d_in[2];
    const float* g1   = (const float*)d_in[3];
    const float* b1   = (const float*)d_in[4];
    const float* m1   = (const float*)d_in[5];
    const float* v1   = (const float*)d_in[6];
    const float* c2w  = (const float*)d_in[7];
    const float* g2   = (const float*)d_in[8];
    const float* b2   = (const float*)d_in[9];
    const float* m2   = (const float*)d_in[10];
    const float* v2   = (const float*)d_in[11];
    const float* binw = (const float*)d_in[12];
    const float* binb = (const float*)d_in[13];
    const float* resw = (const float*)d_in[14];
    const float* resb = (const float*)d_in[15];
    float* out = (float*)d_out;
    char* ws = (char*)d_ws;
    if (ws_size < WS_NEEDED) return;

    uint32_t* bits  = (uint32_t*)(ws + OFF_BITS);
    uint32_t* h13   = (uint32_t*)(ws + OFF_H13);
    uint32_t* ctrl  = (uint32_t*)(ws + OFF_CTRL);
    uint32_t* grank = (uint32_t*)(ws + OFF_GRANK);
    uint64_t* cand  = (uint64_t*)(ws + OFF_CAND);

    k_init<<<(NBIN * NB) / 1024, 256, 0, stream>>>((uint4*)h13);
    k_score<<<dim3(HBLK, NB), 256, 0, stream>>>(cls, bits, h13, grank, ctrl);
    k_compact<<<dim3(CBLK, NB), 256, 0, stream>>>(bits, h13, ctrl, cand);
    k_rank1<<<dim3(CAP / 256, 8, NB), 256, 0, stream>>>(cand, ctrl, grank);
    k_rank2<<<dim3(CAP / 256, NB), 256, 0, stream>>>(cand, ctrl, grank, box, cls, out);
    k_conv<<<dim3(64, NB), 256, 0, stream>>>(c1w, g1, b1, m1, v1, c2w, g2, b2, m2, v2,
                                             binw, binb, resw, resb, out);
}